// Round 1
// baseline (439.583 us; speedup 1.0000x reference)
//
#include <hip/hip_runtime.h>
#include <stdint.h>

#define S_LEN 2048
#define DMODEL 1024
#define NHEAD 16
#define DHEAD 64
#define NBATCH 2
#define NE 4194304   // NBATCH*S_LEN*DMODEL
#define WN 1048576   // DMODEL*DMODEL

typedef unsigned short u16;
typedef float f32x16 __attribute__((ext_vector_type(16)));
typedef __bf16 bf16x8 __attribute__((ext_vector_type(8)));

__device__ __forceinline__ u16 f2bf(float x) {
  union { float f; unsigned u; } v; v.f = x;
  unsigned r = v.u + 0x7fffu + ((v.u >> 16) & 1u);
  return (u16)(r >> 16);
}
__device__ __forceinline__ float bfbits2f(unsigned b) {
  union { unsigned u; float f; } v; v.u = b << 16; return v.f;
}
__device__ __forceinline__ unsigned cvt_pk_bf16(float lo, float hi) {
  unsigned r;
  asm("v_cvt_pk_bf16_f32 %0, %1, %2" : "=v"(r) : "v"(lo), "v"(hi));
  return r;
}
__device__ __forceinline__ void gld_lds16(const void* g, void* l) {
  __builtin_amdgcn_global_load_lds(
      (const __attribute__((address_space(1))) unsigned*)g,
      (__attribute__((address_space(3))) unsigned*)l, 16, 0, 0);
}

// ---------------- convert q,k,v f32 -> bf16 ----------------
__global__ __launch_bounds__(256) void cvt_inputs(
    const float* __restrict__ q, const float* __restrict__ k, const float* __restrict__ v,
    u16* __restrict__ xq, u16* __restrict__ xk, u16* __restrict__ xv)
{
  int i = blockIdx.x * 256 + threadIdx.x;
  const int stride = gridDim.x * 256;
  for (; i < NE / 4; i += stride) {
    float4 a = ((const float4*)q)[i];
    float4 b = ((const float4*)k)[i];
    float4 c = ((const float4*)v)[i];
    ushort4 oa, ob, oc;
    oa.x = f2bf(a.x); oa.y = f2bf(a.y); oa.z = f2bf(a.z); oa.w = f2bf(a.w);
    ob.x = f2bf(b.x); ob.y = f2bf(b.y); ob.z = f2bf(b.z); ob.w = f2bf(b.w);
    oc.x = f2bf(c.x); oc.y = f2bf(c.y); oc.z = f2bf(c.z); oc.w = f2bf(c.w);
    ((ushort4*)xq)[i] = oa;
    ((ushort4*)xk)[i] = ob;
    ((ushort4*)xv)[i] = oc;
  }
}

// ---------------- convert + transpose weights: W[k][n] -> WT[n][k] bf16 ----------------
__global__ __launch_bounds__(256) void wtrans(
    const float* __restrict__ Wq, const float* __restrict__ Wk,
    const float* __restrict__ Wv, const float* __restrict__ Wo,
    u16* __restrict__ oq, u16* __restrict__ ok, u16* __restrict__ ov, u16* __restrict__ oo)
{
  __shared__ u16 t[64][65];
  const float* W; u16* O;
  if (blockIdx.z == 0)      { W = Wq; O = oq; }
  else if (blockIdx.z == 1) { W = Wk; O = ok; }
  else if (blockIdx.z == 2) { W = Wv; O = ov; }
  else                      { W = Wo; O = oo; }
  const int tid = threadIdx.x;
  const int r0 = blockIdx.y * 64, c0 = blockIdx.x * 64;
#pragma unroll
  for (int i = 0; i < 4; ++i) {
    const int row = i * 16 + (tid >> 4);
    const int col = (tid & 15) * 4;
    float4 wv = *(const float4*)(W + (size_t)(r0 + row) * DMODEL + c0 + col);
    t[row][col + 0] = f2bf(wv.x);
    t[row][col + 1] = f2bf(wv.y);
    t[row][col + 2] = f2bf(wv.z);
    t[row][col + 3] = f2bf(wv.w);
  }
  __syncthreads();
#pragma unroll
  for (int i = 0; i < 4; ++i) {
    const int row = i * 16 + (tid >> 4);
    const int col = (tid & 15) * 4;
    ushort4 o;
    o.x = t[col + 0][row]; o.y = t[col + 1][row];
    o.z = t[col + 2][row]; o.w = t[col + 3][row];
    *(ushort4*)(O + (size_t)(c0 + row) * DMODEL + r0 + col) = o;
  }
}

// ---------------- 128x128 bf16 MFMA GEMM, B^T input, global_load_lds staging ----------------
// OUTMODE 0: out = bf16 head-split [(b*H+h)][s][d], val=(acc+bias)*scale
// OUTMODE 1: out = f32 flat [m][n]
template <int OUTMODE>
__device__ __forceinline__ void gemm_core(
    const u16* __restrict__ A, const u16* __restrict__ Bt,
    const float* __restrict__ bias, void* __restrict__ outp,
    float scale, int m0, int n0)
{
  __shared__ u16 As[128 * 32];
  __shared__ u16 Bs[128 * 32];
  const int tid = threadIdx.x;
  const int lane = tid & 63, w = tid >> 6;
  const int q_l = lane & 31, hi = lane >> 5;
  const int wr = w >> 1, wc = w & 1;

  f32x16 acc[2][2];
#pragma unroll
  for (int a = 0; a < 2; ++a)
#pragma unroll
    for (int b = 0; b < 2; ++b)
#pragma unroll
      for (int r = 0; r < 16; ++r) acc[a][b][r] = 0.f;

  const u16* srcA = A + (size_t)(m0 + (tid >> 2)) * DMODEL + (tid & 3) * 8;
  const u16* srcB = Bt + (size_t)(n0 + (tid >> 2)) * DMODEL + (tid & 3) * 8;
  u16* dstA = As + w * 512;
  u16* dstB = Bs + w * 512;

  for (int kt = 0; kt < DMODEL; kt += 32) {
    gld_lds16(srcA + kt, dstA);
    gld_lds16(srcA + kt + (size_t)64 * DMODEL, dstA + 2048);
    gld_lds16(srcB + kt, dstB);
    gld_lds16(srcB + kt + (size_t)64 * DMODEL, dstB + 2048);
    __syncthreads();
#pragma unroll
    for (int kk = 0; kk < 2; ++kk) {
      bf16x8 af[2], bfv[2];
#pragma unroll
      for (int mb = 0; mb < 2; ++mb)
        af[mb] = *reinterpret_cast<const bf16x8*>(&As[(wr * 64 + mb * 32 + q_l) * 32 + kk * 16 + hi * 8]);
#pragma unroll
      for (int nb = 0; nb < 2; ++nb)
        bfv[nb] = *reinterpret_cast<const bf16x8*>(&Bs[(wc * 64 + nb * 32 + q_l) * 32 + kk * 16 + hi * 8]);
#pragma unroll
      for (int mb = 0; mb < 2; ++mb)
#pragma unroll
        for (int nb = 0; nb < 2; ++nb)
          acc[mb][nb] = __builtin_amdgcn_mfma_f32_32x32x16_bf16(af[mb], bfv[nb], acc[mb][nb], 0, 0, 0);
    }
    __syncthreads();
  }

#pragma unroll
  for (int mb = 0; mb < 2; ++mb) {
#pragma unroll
    for (int nb = 0; nb < 2; ++nb) {
      const int n = n0 + wc * 64 + nb * 32 + q_l;
      const float bn = bias[n];
#pragma unroll
      for (int r = 0; r < 16; ++r) {
        const int m = m0 + wr * 64 + mb * 32 + (r & 3) + 8 * (r >> 2) + 4 * hi;
        const float val = (acc[mb][nb][r] + bn) * scale;
        if (OUTMODE == 0) {
          const int bb = m >> 11, s = m & 2047, hh = n >> 6, d = n & 63;
          ((u16*)outp)[(((size_t)(bb * NHEAD + hh)) * S_LEN + s) * DHEAD + d] = f2bf(val);
        } else {
          ((float*)outp)[(size_t)m * DMODEL + n] = val;
        }
      }
    }
  }
}

__global__ __launch_bounds__(256) void gemm_qkv(
    const u16* __restrict__ xq, const u16* __restrict__ xk, const u16* __restrict__ xv,
    const u16* __restrict__ wqt, const u16* __restrict__ wkt, const u16* __restrict__ wvt,
    const float* __restrict__ bq, const float* __restrict__ bk, const float* __restrict__ bv,
    u16* __restrict__ qh, u16* __restrict__ kh, u16* __restrict__ vh)
{
  const u16 *A, *Bt; const float* bias; u16* O; float scale;
  if (blockIdx.z == 0)      { A = xq; Bt = wqt; bias = bq; O = qh; scale = 0.125f; }
  else if (blockIdx.z == 1) { A = xk; Bt = wkt; bias = bk; O = kh; scale = 1.f; }
  else                      { A = xv; Bt = wvt; bias = bv; O = vh; scale = 1.f; }
  gemm_core<0>(A, Bt, bias, O, scale, blockIdx.y * 128, blockIdx.x * 128);
}

__global__ __launch_bounds__(256) void gemm_out(
    const u16* __restrict__ ctx, const u16* __restrict__ wot,
    const float* __restrict__ bo, float* __restrict__ out)
{
  gemm_core<1>(ctx, wot, bo, out, 1.f, blockIdx.y * 128, blockIdx.x * 128);
}

// ---------------- transpose Vh[bh][s][d] -> Vt[bh][d][s] ----------------
__global__ __launch_bounds__(256) void vtrans(const u16* __restrict__ vh, u16* __restrict__ vt)
{
  __shared__ u16 t[64][72];
  const int tid = threadIdx.x;
  const int bh = blockIdx.y;
  const int s0 = blockIdx.x * 64;
  const u16* src = vh + (size_t)bh * S_LEN * DHEAD;
  u16* dst = vt + (size_t)bh * DHEAD * S_LEN;
#pragma unroll
  for (int i = 0; i < 2; ++i) {
    const int row = i * 32 + (tid >> 3);
    const int c8 = (tid & 7) * 8;
    *(uint4*)&t[row][c8] = *(const uint4*)(src + (size_t)(s0 + row) * DHEAD + c8);
  }
  __syncthreads();
#pragma unroll
  for (int i = 0; i < 2; ++i) {
    const int d = i * 32 + (tid >> 3);
    const int c8 = (tid & 7) * 8;
    unsigned p0 = (unsigned)t[c8 + 0][d] | ((unsigned)t[c8 + 1][d] << 16);
    unsigned p1 = (unsigned)t[c8 + 2][d] | ((unsigned)t[c8 + 3][d] << 16);
    unsigned p2 = (unsigned)t[c8 + 4][d] | ((unsigned)t[c8 + 5][d] << 16);
    unsigned p3 = (unsigned)t[c8 + 6][d] | ((unsigned)t[c8 + 7][d] << 16);
    uint4 o; o.x = p0; o.y = p1; o.z = p2; o.w = p3;
    *(uint4*)(dst + (size_t)d * S_LEN + s0 + c8) = o;
  }
}

// ---------------- fused attention: QK^T -> softmax -> attn write + PV ----------------
// grid (64 q-blocks, 32 bh), 512 threads (8 waves). Wave w owns k-range [w*256, w*256+256).
// Swapped QK (mfma(K,Q)) so each lane owns one q-column; P kept in regs as packed bf16.
__global__ __launch_bounds__(512) void attn_fused(
    const u16* __restrict__ qh, const u16* __restrict__ kh,
    const u16* __restrict__ vt, const float* __restrict__ mask,
    float* __restrict__ attn_out, u16* __restrict__ ctx_out)
{
  __shared__ float smaskv[S_LEN];
  __shared__ float sctx[32][64];
  __shared__ float srow[8][32];
  __shared__ float sinv[32];
  __shared__ float sbuf[8][32][33];   // per-wave [k_local][q] staging for coalesced attn store

  const int tid = threadIdx.x;
  const int lane = tid & 63, w = tid >> 6;
  const int q_l = lane & 31, hi = lane >> 5;
  const int qb = blockIdx.x, bh = blockIdx.y;
  const int b = bh >> 4, h = bh & 15;
  const int q0 = qb * 32;

  const u16* Qp = qh + (size_t)bh * S_LEN * DHEAD;
  const u16* Kp = kh + (size_t)bh * S_LEN * DHEAD;
  const u16* Vp = vt + (size_t)bh * DHEAD * S_LEN;

  for (int i = tid; i < S_LEN / 4; i += 512) {
    float4 m4 = ((const float4*)(mask + (size_t)b * S_LEN))[i];
    smaskv[4 * i + 0] = m4.x * -1e9f;
    smaskv[4 * i + 1] = m4.y * -1e9f;
    smaskv[4 * i + 2] = m4.z * -1e9f;
    smaskv[4 * i + 3] = m4.w * -1e9f;
  }
  for (int i = tid; i < 32 * 64; i += 512) (&sctx[0][0])[i] = 0.f;
  __syncthreads();

  // Q fragments (B-operand of swapped mfma): lane holds Q[q0+q_l][c*16 + hi*8 + i]
  bf16x8 qf[4];
  {
    const u16* qrow = Qp + (size_t)(q0 + q_l) * DHEAD + hi * 8;
#pragma unroll
    for (int c = 0; c < 4; ++c) qf[c] = *reinterpret_cast<const bf16x8*>(qrow + c * 16);
  }

  unsigned pk[8][8];   // packed bf16 P, [tile][2*g + half], unnormalized exp
  float rsum = 0.f;
  const int k0w = w * 256;

#pragma unroll
  for (int t = 0; t < 8; ++t) {
    const int k0 = k0w + t * 32;
    const u16* krow = Kp + (size_t)(k0 + q_l) * DHEAD + hi * 8;
    bf16x8 kf[4];
#pragma unroll
    for (int c = 0; c < 4; ++c) kf[c] = *reinterpret_cast<const bf16x8*>(krow + c * 16);
    f32x16 acc;
#pragma unroll
    for (int r = 0; r < 16; ++r) acc[r] = 0.f;
#pragma unroll
    for (int c = 0; c < 4; ++c)
      acc = __builtin_amdgcn_mfma_f32_32x32x16_bf16(kf[c], qf[c], acc, 0, 0, 0);
    float p[16];
#pragma unroll
    for (int r = 0; r < 16; ++r) {
      const int kl = (r & 3) + 8 * (r >> 2) + 4 * hi;   // C/D row mapping (k index)
      p[r] = __expf(acc[r] + smaskv[k0 + kl]);
      rsum += p[r];
    }
#pragma unroll
    for (int g = 0; g < 4; ++g) {
      pk[t][2 * g + 0] = cvt_pk_bf16(p[4 * g + 0], p[4 * g + 1]);
      pk[t][2 * g + 1] = cvt_pk_bf16(p[4 * g + 2], p[4 * g + 3]);
    }
  }

  rsum += __shfl_xor(rsum, 32, 64);
  if (lane < 32) srow[w][lane] = rsum;
  __syncthreads();
  float tot = 0.f;
#pragma unroll
  for (int ww = 0; ww < 8; ++ww) tot += srow[ww][q_l];
  const float inv = 1.0f / tot;
  if (w == 0 && lane < 32) sinv[lane] = inv;

  float* arow = attn_out + ((size_t)bh * S_LEN + q0) * S_LEN;
  f32x16 cacc[2];
#pragma unroll
  for (int db = 0; db < 2; ++db)
#pragma unroll
    for (int r = 0; r < 16; ++r) cacc[db][r] = 0.f;

#pragma unroll
  for (int t = 0; t < 8; ++t) {
    const int k0 = k0w + t * 32;
    // normalized f32 attn values -> per-wave LDS tile ([k][q] layout, conflict-free)
#pragma unroll
    for (int g = 0; g < 4; ++g) {
      const int kb = 8 * g + 4 * hi;
      sbuf[w][kb + 0][q_l] = bfbits2f(pk[t][2 * g] & 0xffffu) * inv;
      sbuf[w][kb + 1][q_l] = bfbits2f(pk[t][2 * g] >> 16) * inv;
      sbuf[w][kb + 2][q_l] = bfbits2f(pk[t][2 * g + 1] & 0xffffu) * inv;
      sbuf[w][kb + 3][q_l] = bfbits2f(pk[t][2 * g + 1] >> 16) * inv;
    }
    // PV: build A-fragments via permlane32_swap of packed P, B = Vt rows (contiguous)
#pragma unroll
    for (int s2 = 0; s2 < 2; ++s2) {
      unsigned a0 = pk[t][4 * s2 + 0], b0 = pk[t][4 * s2 + 2];
      unsigned a1 = pk[t][4 * s2 + 1], b1 = pk[t][4 * s2 + 3];
      asm volatile("v_permlane32_swap_b32 %0, %1" : "+v"(a0), "+v"(b0));
      asm volatile("v_permlane32_swap_b32 %0, %1" : "+v"(a1), "+v"(b1));
      uint4 frw; frw.x = a0; frw.y = a1; frw.z = b0; frw.w = b1;
      bf16x8 pa = __builtin_bit_cast(bf16x8, frw);
#pragma unroll
      for (int db = 0; db < 2; ++db) {
        const u16* vrow = Vp + (size_t)(db * 32 + q_l) * S_LEN + k0 + s2 * 16 + hi * 8;
        bf16x8 vf = *reinterpret_cast<const bf16x8*>(vrow);
        cacc[db] = __builtin_amdgcn_mfma_f32_32x32x16_bf16(pa, vf, cacc[db], 0, 0, 0);
      }
    }
    // coalesced attn store (wave-internal RAW on sbuf, program-ordered)
#pragma unroll
    for (int j = 0; j < 4; ++j) {
      const int row = j * 8 + (lane >> 3);
      const int c4 = (lane & 7) * 4;
      float4 vv;
      vv.x = sbuf[w][c4 + 0][row];
      vv.y = sbuf[w][c4 + 1][row];
      vv.z = sbuf[w][c4 + 2][row];
      vv.w = sbuf[w][c4 + 3][row];
      *(float4*)(arow + (size_t)row * S_LEN + k0 + c4) = vv;
    }
  }

  // cross-wave ctx reduction
#pragma unroll
  for (int db = 0; db < 2; ++db)
#pragma unroll
    for (int r = 0; r < 16; ++r) {
      const int qq = (r & 3) + 8 * (r >> 2) + 4 * hi;
      atomicAdd(&sctx[qq][db * 32 + q_l], cacc[db][r]);
    }
  __syncthreads();
  {
    const int row = tid >> 4;
    const int d0 = (tid & 15) * 4;
    const float iv = sinv[row];
    ushort4 o;
    o.x = f2bf(sctx[row][d0 + 0] * iv);
    o.y = f2bf(sctx[row][d0 + 1] * iv);
    o.z = f2bf(sctx[row][d0 + 2] * iv);
    o.w = f2bf(sctx[row][d0 + 3] * iv);
    *(ushort4*)(ctx_out + (((size_t)(b * S_LEN + q0 + row)) * DMODEL + h * DHEAD + d0)) = o;
  }
}

extern "C" void kernel_launch(void* const* d_in, const int* in_sizes, int n_in,
                              void* d_out, int out_size, void* d_ws, size_t ws_size,
                              hipStream_t stream)
{
  (void)in_sizes; (void)n_in; (void)out_size; (void)ws_size;
  const float* v    = (const float*)d_in[0];
  const float* k    = (const float*)d_in[1];
  const float* q    = (const float*)d_in[2];
  const float* mask = (const float*)d_in[3];
  const float* Wq   = (const float*)d_in[4];
  const float* bq   = (const float*)d_in[5];
  const float* Wk   = (const float*)d_in[6];
  const float* bk   = (const float*)d_in[7];
  const float* Wv   = (const float*)d_in[8];
  const float* bv   = (const float*)d_in[9];
  const float* Wo   = (const float*)d_in[10];
  const float* bo   = (const float*)d_in[11];

  u16* ws16 = (u16*)d_ws;
  u16* xq  = ws16;
  u16* xk  = ws16 + (size_t)1 * NE;
  u16* xv  = ws16 + (size_t)2 * NE;
  u16* qh  = ws16 + (size_t)3 * NE;
  u16* kh  = ws16 + (size_t)4 * NE;
  u16* vh  = ws16 + (size_t)5 * NE;
  u16* wqt = ws16 + (size_t)6 * NE;
  u16* wkt = wqt + WN;
  u16* wvt = wkt + WN;
  u16* wot = wvt + WN;
  u16* vt  = xq;   // alias: xq dead after gemm_qkv
  u16* ctx = xk;   // alias: xk dead after gemm_qkv

  float* outp  = (float*)d_out;
  float* attnp = outp + (size_t)NE;

  cvt_inputs<<<dim3(1024), dim3(256), 0, stream>>>(q, k, v, xq, xk, xv);
  wtrans<<<dim3(16, 16, 4), dim3(256), 0, stream>>>(Wq, Wk, Wv, Wo, wqt, wkt, wvt, wot);
  gemm_qkv<<<dim3(8, 32, 3), dim3(256), 0, stream>>>(xq, xk, xv, wqt, wkt, wvt,
                                                     bq, bk, bv, qh, kh, vh);
  vtrans<<<dim3(32, 32), dim3(256), 0, stream>>>(vh, vt);
  attn_fused<<<dim3(64, 32), dim3(512), 0, stream>>>(qh, kh, vt, mask, attnp, ctx);
  gemm_out<<<dim3(8, 32), dim3(256), 0, stream>>>(ctx, wot, bo, outp);
}